// Round 6
// baseline (872.748 us; speedup 1.0000x reference)
//
#include <hip/hip_runtime.h>

#define N_NODES 50000
#define N_EDGES 800000
#define NODE_IN 256
#define EDGE_IN 64
#define HID 128
#define OUTD 16
#define LN_EPS 1e-5f
#define NCHUNK 128
#define EPC (N_EDGES / NCHUNK)   // 6250 edges per chunk

typedef __attribute__((ext_vector_type(4))) float f32x4;
typedef __attribute__((ext_vector_type(8))) _Float16 half8;
typedef __attribute__((ext_vector_type(4))) _Float16 half4;

__device__ __forceinline__ float gelu_exact(float x) {
    return 0.5f * x * (1.0f + erff(x * 0.70710678118654752f));
}

// ---------------------------------------------------------------------------
// Setup: transpose weights to [col][k] fp16 (MFMA B fragments become 16B loads)
// ---------------------------------------------------------------------------
__global__ void setup_kernel(const float* __restrict__ Wn, const float* __restrict__ We,
                             _Float16* __restrict__ WTn, _Float16* __restrict__ WTe) {
    int t = blockIdx.x * blockDim.x + threadIdx.x;
    int stride = gridDim.x * blockDim.x;
    for (int i = t; i < HID * NODE_IN; i += stride) {
        int n = i >> 8, k = i & 255;
        WTn[i] = (_Float16)Wn[k * HID + n];
    }
    for (int i = t; i < HID * EDGE_IN; i += stride) {
        int n = i >> 6, k = i & 63;
        WTe[i] = (_Float16)We[k * HID + n];
    }
}

// ---------------------------------------------------------------------------
// Deterministic stable counting sort by dst (round-4 proven machinery).
// Pass A: per-chunk histograms; 4 blocks cooperate per chunk.
// ---------------------------------------------------------------------------
__global__ __launch_bounds__(256) void hist_kernel(const int* __restrict__ dst,
                                                   int* __restrict__ hist) {
    const int k = blockIdx.x >> 2;
    const int part = blockIdx.x & 3;
    int* hk = hist + k * N_NODES;
    const int beg = k * EPC;
    for (int i = part * 256 + threadIdx.x; i < EPC; i += 1024)
        atomicAdd(&hk[dst[beg + i]], 1);
}

// Pass B1: per-node totals across chunks.
__global__ __launch_bounds__(256) void tot_kernel(const int* __restrict__ hist,
                                                  int* __restrict__ tot) {
    int n = blockIdx.x * 256 + threadIdx.x;
    if (n < N_NODES) {
        int s = 0;
        #pragma unroll 8
        for (int k = 0; k < NCHUNK; ++k) s += hist[k * N_NODES + n];
        tot[n] = s;
    }
}

// Scan over tot -> offs (exclusive).  49 blocks x 1024 elements.
__global__ __launch_bounds__(256) void scan1_kernel(const int* __restrict__ tot,
                                                    int* __restrict__ offs,
                                                    int* __restrict__ btot) {
    __shared__ int lsum[256];
    const int t = threadIdx.x;
    const int base = blockIdx.x * 1024 + t * 4;
    int v[4]; int s = 0;
    #pragma unroll
    for (int j = 0; j < 4; ++j) {
        int idx = base + j;
        v[j] = (idx < N_NODES) ? tot[idx] : 0;
        s += v[j];
    }
    lsum[t] = s;
    __syncthreads();
    for (int d = 1; d < 256; d <<= 1) {
        int x = (t >= d) ? lsum[t - d] : 0;
        __syncthreads();
        lsum[t] += x;
        __syncthreads();
    }
    int excl = lsum[t] - s;
    if (t == 255) btot[blockIdx.x] = lsum[255];
    int run = excl;
    #pragma unroll
    for (int j = 0; j < 4; ++j) {
        int idx = base + j;
        if (idx < N_NODES) offs[idx] = run;
        run += v[j];
    }
}

__global__ __launch_bounds__(256) void scan2_kernel(int* __restrict__ offs,
                                                    const int* __restrict__ btot) {
    int s = 0;
    for (int i = 0; i < (int)blockIdx.x; ++i) s += btot[i];
    const int t = threadIdx.x;
    const int base = blockIdx.x * 1024 + t * 4;
    #pragma unroll
    for (int j = 0; j < 4; ++j) {
        int idx = base + j;
        if (idx < N_NODES) offs[idx] += s;
    }
    if (blockIdx.x == 0 && t == 0) offs[N_NODES] = N_EDGES;
}

// Pass B2: convert hist rows to per-chunk starting cursors (in place).
__global__ __launch_bounds__(256) void cursor_kernel(const int* __restrict__ offs,
                                                     int* __restrict__ hist) {
    int n = blockIdx.x * 256 + threadIdx.x;
    if (n < N_NODES) {
        int running = offs[n];
        #pragma unroll 4
        for (int k = 0; k < NCHUNK; ++k) {
            int c = hist[k * N_NODES + n];
            hist[k * N_NODES + n] = running;
            running += c;
        }
    }
}

// Pass C: stable placement (round-4 semantics, ILP-optimized rank loop).
// One block per chunk; 256-edge groups processed in barrier-enforced order.
// ld[] padded to 256 with -1 so the rank scan is a fully-unrolled int4 loop
// (64 independent ds_read_b128 + branch-free ALU) instead of 256 dependent
// scalar LDS broadcasts -- that serial chain was the 269us in round 4.
__global__ __launch_bounds__(256) void place_kernel(const int* __restrict__ src,
                                                    const int* __restrict__ dst,
                                                    int* __restrict__ cur,
                                                    int* __restrict__ perm,
                                                    int* __restrict__ psrc) {
    __shared__ __align__(16) int ld[256];
    __shared__ int ls[256];
    __shared__ int lb[256];
    const int k = blockIdx.x;
    const int t = threadIdx.x;
    int* curk = cur + k * N_NODES;
    const int cbeg = k * EPC;
    const int ngroups = (EPC + 255) / 256;   // 25, uniform across blocks
    for (int g = 0; g < ngroups; ++g) {
        const int gbeg = cbeg + g * 256;
        const int count = min(256, cbeg + EPC - gbeg);
        __syncthreads();                      // protect LDS reuse
        if (t < count) { ld[t] = dst[gbeg + t]; ls[t] = src[gbeg + t]; }
        else ld[t] = -1;                      // pad: never matches a valid dst
        __syncthreads();
        if (t < count) {
            const int d = ld[t];
            int rank = 0, total = 0, leader = 256;
            #pragma unroll
            for (int i = 0; i < 256; i += 4) {
                int4 a = *(const int4*)(ld + i);
                int m0 = (a.x == d), m1 = (a.y == d), m2 = (a.z == d), m3 = (a.w == d);
                total += m0 + m1 + m2 + m3;
                rank += (m0 & (i + 0 < t)) + (m1 & (i + 1 < t))
                      + (m2 & (i + 2 < t)) + (m3 & (i + 3 < t));
                leader = min(leader, m0 ? (i + 0) : 256);
                leader = min(leader, m1 ? (i + 1) : 256);
                leader = min(leader, m2 ? (i + 2) : 256);
                leader = min(leader, m3 ? (i + 3) : 256);
            }
            if (rank == 0) {                  // leader for this dst in this group
                int bse = atomicAdd(&curk[d], total);
                lb[t] = bse;
            }
            __syncthreads();
            int pos = lb[leader] + rank;
            perm[pos] = gbeg + t;
            psrc[pos] = ls[t];
        } else {
            __syncthreads();
        }
    }
}

// ---------------------------------------------------------------------------
// Node projection: hv = LN(GELU(X @ Wn)), stored fp16 PERMUTED:
// hv[row*128 + x*8 + c] = value at col (16c + x).
// ---------------------------------------------------------------------------
__global__ __launch_bounds__(256) void node_kernel(
    const float* __restrict__ X,
    const _Float16* __restrict__ WT,    // [HID][NODE_IN]
    const float* __restrict__ g, const float* __restrict__ b,
    _Float16* __restrict__ hv)
{
    __shared__ __align__(16) _Float16 lA[64 * 72];
    __shared__ __align__(16) _Float16 lB[128 * 72];

    const int t = threadIdx.x;
    const int wave = t >> 6, lane = t & 63;
    const int x15 = lane & 15, quad = lane >> 4;
    const int row0 = blockIdx.x * 64;

    float gc[8], bc[8];
    #pragma unroll
    for (int c = 0; c < 8; ++c) { gc[c] = g[16 * c + x15]; bc[c] = b[16 * c + x15]; }

    f32x4 acc[8];
    #pragma unroll
    for (int c = 0; c < 8; ++c) acc[c] = (f32x4)(0.0f);

    for (int kc = 0; kc < 4; ++kc) {
        const int k0 = kc * 64;
        __syncthreads();
        #pragma unroll
        for (int j = 0; j < 4; ++j) {
            int idx = j * 1024 + t * 4;
            int r = idx >> 6, kk = idx & 63;
            int grow = row0 + r;
            float4 v = make_float4(0.f, 0.f, 0.f, 0.f);
            if (grow < N_NODES) v = *(const float4*)(X + grow * NODE_IN + k0 + kk);
            half4 h4;
            h4[0] = (_Float16)v.x; h4[1] = (_Float16)v.y;
            h4[2] = (_Float16)v.z; h4[3] = (_Float16)v.w;
            *(half4*)(lA + r * 72 + kk) = h4;
        }
        #pragma unroll
        for (int j = 0; j < 4; ++j) {
            int idx = j * 2048 + t * 8;
            int n = idx >> 6, kk = idx & 63;
            half8 v = *(const half8*)(WT + n * NODE_IN + k0 + kk);
            *(half8*)(lB + n * 72 + kk) = v;
        }
        __syncthreads();
        #pragma unroll
        for (int ks = 0; ks < 2; ++ks) {
            half8 a = *(const half8*)(lA + (wave * 16 + x15) * 72 + ks * 32 + quad * 8);
            #pragma unroll
            for (int c = 0; c < 8; ++c) {
                half8 bb = *(const half8*)(lB + (c * 16 + x15) * 72 + ks * 32 + quad * 8);
                acc[c] = __builtin_amdgcn_mfma_f32_16x16x32_f16(a, bb, acc[c], 0, 0, 0);
            }
        }
    }

    float v[8][4], s[4], sq[4];
    #pragma unroll
    for (int r = 0; r < 4; ++r) { s[r] = 0.f; sq[r] = 0.f; }
    #pragma unroll
    for (int c = 0; c < 8; ++c)
        #pragma unroll
        for (int r = 0; r < 4; ++r) {
            float x = gelu_exact(acc[c][r]);
            v[c][r] = x; s[r] += x; sq[r] += x * x;
        }
    #pragma unroll
    for (int m = 1; m <= 8; m <<= 1)
        #pragma unroll
        for (int r = 0; r < 4; ++r) {
            s[r]  += __shfl_xor(s[r],  m, 64);
            sq[r] += __shfl_xor(sq[r], m, 64);
        }
    #pragma unroll
    for (int r = 0; r < 4; ++r) {
        int row = row0 + wave * 16 + quad * 4 + r;
        if (row >= N_NODES) continue;
        float mean = s[r] * (1.f / 128.f);
        float var  = sq[r] * (1.f / 128.f) - mean * mean;
        float rstd = rsqrtf(var + LN_EPS);
        half8 o;
        #pragma unroll
        for (int c = 0; c < 8; ++c)
            o[c] = (_Float16)((v[c][r] - mean) * rstd * gc[c] + bc[c]);
        *(half8*)(hv + row * HID + x15 * 8) = o;
    }
}

// ---------------------------------------------------------------------------
// Edge projection in SORTED order: block handles 64 sorted positions, gathers
// full 256B EF rows via perm, MFMA -> LN -> exp, writes hesort CONTIGUOUS.
// ---------------------------------------------------------------------------
__global__ __launch_bounds__(256) void eproj_kernel(
    const float* __restrict__ EF,
    const int* __restrict__ perm,
    const _Float16* __restrict__ WT,    // [HID][EDGE_IN]
    const float* __restrict__ g, const float* __restrict__ b,
    _Float16* __restrict__ hesort)
{
    __shared__ __align__(16) _Float16 lA[64 * 72];
    __shared__ int lsid[64];

    const int t = threadIdx.x;
    const int wave = t >> 6, lane = t & 63;
    const int x15 = lane & 15, quad = lane >> 4;
    const int p0 = blockIdx.x * 64;

    half8 Bf[8][2];
    #pragma unroll
    for (int c = 0; c < 8; ++c)
        #pragma unroll
        for (int ks = 0; ks < 2; ++ks)
            Bf[c][ks] = *(const half8*)(WT + (c * 16 + x15) * EDGE_IN + ks * 32 + quad * 8);

    float gc[8], bc[8];
    #pragma unroll
    for (int c = 0; c < 8; ++c) { gc[c] = g[16 * c + x15]; bc[c] = b[16 * c + x15]; }

    if (t < 64) lsid[t] = perm[p0 + t];
    __syncthreads();

    // gather 64 EF rows (256B full-row gathers: 16 threads x 16B per row)
    #pragma unroll
    for (int j = 0; j < 4; ++j) {
        int idx = j * 1024 + t * 4;
        int r = idx >> 6, kk = idx & 63;
        float4 v = *(const float4*)(EF + (size_t)lsid[r] * EDGE_IN + kk);
        half4 h4;
        h4[0] = (_Float16)v.x; h4[1] = (_Float16)v.y;
        h4[2] = (_Float16)v.z; h4[3] = (_Float16)v.w;
        *(half4*)(lA + r * 72 + kk) = h4;
    }
    __syncthreads();

    f32x4 acc[8];
    #pragma unroll
    for (int c = 0; c < 8; ++c) acc[c] = (f32x4)(0.0f);
    #pragma unroll
    for (int ks = 0; ks < 2; ++ks) {
        half8 a = *(const half8*)(lA + (wave * 16 + x15) * 72 + ks * 32 + quad * 8);
        #pragma unroll
        for (int c = 0; c < 8; ++c)
            acc[c] = __builtin_amdgcn_mfma_f32_16x16x32_f16(a, Bf[c][ks], acc[c], 0, 0, 0);
    }

    float s[4], sq[4];
    #pragma unroll
    for (int r = 0; r < 4; ++r) { s[r] = 0.f; sq[r] = 0.f; }
    #pragma unroll
    for (int c = 0; c < 8; ++c)
        #pragma unroll
        for (int r = 0; r < 4; ++r) { float x = acc[c][r]; s[r] += x; sq[r] += x * x; }
    #pragma unroll
    for (int m = 1; m <= 8; m <<= 1)
        #pragma unroll
        for (int r = 0; r < 4; ++r) {
            s[r]  += __shfl_xor(s[r],  m, 64);
            sq[r] += __shfl_xor(sq[r], m, 64);
        }

    #pragma unroll
    for (int r = 0; r < 4; ++r) {
        int erow = wave * 16 + quad * 4 + r;
        float mean = s[r] * (1.f / 128.f);
        float var  = sq[r] * (1.f / 128.f) - mean * mean;
        float rstd = rsqrtf(var + LN_EPS);
        half8 o;
        #pragma unroll
        for (int c = 0; c < 8; ++c)
            o[c] = (_Float16)__expf((acc[c][r] - mean) * rstd * gc[c] + bc[c]);
        *(half8*)(hesort + (size_t)(p0 + erow) * HID + x15 * 8) = o;
    }
}

// ---------------------------------------------------------------------------
// Streaming segment-sum: wave per node; he rows consecutive (sorted), hv
// gathered (L2/L3-hot); fp32 accumulate; one 512B store per node.
// ---------------------------------------------------------------------------
__global__ __launch_bounds__(256) void agg2_kernel(
    const _Float16* __restrict__ hesort,
    const int* __restrict__ psrc, const int* __restrict__ offs,
    const _Float16* __restrict__ hv,
    float* __restrict__ h)
{
    const int t = threadIdx.x;
    const int wave = t >> 6, lane = t & 63;
    const int x15 = lane & 15, quad = lane >> 4;
    const int n = blockIdx.x * 4 + wave;   // 12500 * 4 = 50000 exact

    const int beg = offs[n], end = offs[n + 1];

    float vacc[8];
    #pragma unroll
    for (int c = 0; c < 8; ++c) vacc[c] = 0.f;

    for (int e0 = beg; e0 < end; e0 += 8) {
        int e1 = e0 + quad, e2 = e0 + 4 + quad;
        bool v1 = e1 < end, v2 = e2 < end;
        int c1 = v1 ? e1 : beg, c2 = v2 ? e2 : beg;
        int s1 = psrc[c1], s2 = psrc[c2];
        half8 a1 = *(const half8*)(hesort + (size_t)c1 * HID + x15 * 8);
        half8 a2 = *(const half8*)(hesort + (size_t)c2 * HID + x15 * 8);
        half8 b1 = *(const half8*)(hv + (size_t)s1 * HID + x15 * 8);
        half8 b2 = *(const half8*)(hv + (size_t)s2 * HID + x15 * 8);
        if (v1) {
            #pragma unroll
            for (int c = 0; c < 8; ++c) vacc[c] += (float)a1[c] * (float)b1[c];
        }
        if (v2) {
            #pragma unroll
            for (int c = 0; c < 8; ++c) vacc[c] += (float)a2[c] * (float)b2[c];
        }
    }

    float o8[8];
    #pragma unroll
    for (int c = 0; c < 8; ++c) {
        float v = vacc[c];
        v += __shfl_xor(v, 16, 64);
        v += __shfl_xor(v, 32, 64);
        o8[c] = v;
    }
    if (quad == 0) {
        float* hp = h + (size_t)n * HID + x15 * 8;   // permuted layout p = x15*8 + c
        *(float4*)hp = make_float4(o8[0], o8[1], o8[2], o8[3]);
        *(float4*)(hp + 4) = make_float4(o8[4], o8[5], o8[6], o8[7]);
    }
}

// ---------------------------------------------------------------------------
// Out projection: out = LN(GELU(h @ Wout)).  Un-permutes h in LDS staging.
// ---------------------------------------------------------------------------
__global__ __launch_bounds__(256) void out_kernel(
    const float* __restrict__ h,
    const float* __restrict__ W,       // [128][16]
    const float* __restrict__ g, const float* __restrict__ b,
    float* __restrict__ out)
{
    __shared__ float lW[HID * OUTD];
    __shared__ float lh[16][HID];
    const int t = threadIdx.x;
    const int node0 = blockIdx.x * 16;

    for (int i = t; i < HID * OUTD; i += 256) lW[i] = W[i];
    for (int i = t; i < 16 * HID; i += 256) {
        int row = i >> 7, p = i & 127;
        int k = 16 * (p & 7) + (p >> 3);     // un-permute: p = x*8 + c -> k = 16c + x
        int grow = node0 + row;
        lh[row][k] = (grow < N_NODES) ? h[grow * HID + p] : 0.f;
    }
    __syncthreads();

    const int i = t >> 4, j = t & 15;
    float acc = 0.f;
    #pragma unroll 8
    for (int k = 0; k < HID; ++k)
        acc = fmaf(lh[i][k], lW[k * OUTD + j], acc);
    float x = gelu_exact(acc);
    float s = x, sq = x * x;
    #pragma unroll
    for (int m = 1; m <= 8; m <<= 1) {
        s  += __shfl_xor(s,  m, 64);
        sq += __shfl_xor(sq, m, 64);
    }
    float mean = s * (1.f / 16.f);
    float var  = sq * (1.f / 16.f) - mean * mean;
    float rstd = rsqrtf(var + LN_EPS);
    int grow = node0 + i;
    if (grow < N_NODES) out[grow * OUTD + j] = (x - mean) * rstd * g[j] + b[j];
}

// ---------------------------------------------------------------------------
extern "C" void kernel_launch(void* const* d_in, const int* in_sizes, int n_in,
                              void* d_out, int out_size, void* d_ws, size_t ws_size,
                              hipStream_t stream) {
    const float* node_feats = (const float*)d_in[0];
    const float* edge_feats = (const float*)d_in[1];
    const int*   src        = (const int*)d_in[2];
    const int*   dst        = (const int*)d_in[3];
    const float* W_node     = (const float*)d_in[4];
    const float* g_node     = (const float*)d_in[5];
    const float* b_node     = (const float*)d_in[6];
    const float* W_edge     = (const float*)d_in[7];
    const float* g_edge     = (const float*)d_in[8];
    const float* b_edge     = (const float*)d_in[9];
    const float* W_out      = (const float*)d_in[10];
    const float* g_out      = (const float*)d_in[11];
    const float* b_out      = (const float*)d_in[12];
    float* out = (float*)d_out;

    char* ws = (char*)d_ws;
    size_t o = 0;
    _Float16* hv  = (_Float16*)(ws + o); o += (size_t)N_NODES * HID * 2;        // 12.8 MB
    float*    h   = (float*)(ws + o);    o += (size_t)N_NODES * HID * 4;        // 25.6 MB
    _Float16* WTn = (_Float16*)(ws + o); o += (size_t)HID * NODE_IN * 2;        // 64 KB
    _Float16* WTe = (_Float16*)(ws + o); o += (size_t)HID * EDGE_IN * 2;        // 16 KB
    int* tot  = (int*)(ws + o); o += (size_t)N_NODES * 4;                       // 200 KB
    int* offs = (int*)(ws + o); o += (size_t)(N_NODES + 16) * 4;                // 200 KB
    int* btot = (int*)(ws + o); o += 1024;
    int* hist = (int*)(ws + o); o += (size_t)NCHUNK * N_NODES * 4;              // 25.6 MB
    int* perm = (int*)(ws + o); o += (size_t)N_EDGES * 4;                       // 3.2 MB
    int* psrc = (int*)(ws + o); o += (size_t)N_EDGES * 4;                       // 3.2 MB
    _Float16* hesort = (_Float16*)(ws + o);                                     // +204.8 MB (fits: round-4 proved >=280.8 MB)

    hipMemsetAsync(hist, 0, (size_t)NCHUNK * N_NODES * sizeof(int), stream);
    setup_kernel<<<128, 256, 0, stream>>>(W_node, W_edge, WTn, WTe);
    node_kernel<<<(N_NODES + 63) / 64, 256, 0, stream>>>(node_feats, WTn, g_node, b_node, hv);
    hist_kernel<<<NCHUNK * 4, 256, 0, stream>>>(dst, hist);
    tot_kernel<<<(N_NODES + 255) / 256, 256, 0, stream>>>(hist, tot);
    scan1_kernel<<<49, 256, 0, stream>>>(tot, offs, btot);
    scan2_kernel<<<49, 256, 0, stream>>>(offs, btot);
    cursor_kernel<<<(N_NODES + 255) / 256, 256, 0, stream>>>(offs, hist);
    place_kernel<<<NCHUNK, 256, 0, stream>>>(src, dst, hist, perm, psrc);
    eproj_kernel<<<N_EDGES / 64, 256, 0, stream>>>(edge_feats, perm, WTe, g_edge, b_edge, hesort);
    agg2_kernel<<<N_NODES / 4, 256, 0, stream>>>(hesort, psrc, offs, hv, h);
    out_kernel<<<(N_NODES + 15) / 16, 256, 0, stream>>>(h, W_out, g_out, b_out, out);
}